// Round 16
// baseline (142.652 us; speedup 1.0000x reference)
//
#include <hip/hip_runtime.h>
#include <hip/hip_bf16.h>
#include <stdint.h>

#define KAUG 192   // 128 LoRA cols + 8 gate cols + 56 zero pad (multiple of 64)
#define M_ROWS 16384

typedef __attribute__((ext_vector_type(8))) __bf16 bf16x8;
typedef __attribute__((ext_vector_type(4))) float f32x4;

__device__ __forceinline__ unsigned short f2b(float f) {
  unsigned int u = __builtin_bit_cast(unsigned int, f);
  u = (u + 0x7fffu + ((u >> 16) & 1u)) >> 16;
  return (unsigned short)u;
}

__device__ __forceinline__ void lds_load16(const unsigned short* g, unsigned short* l) {
  __builtin_amdgcn_global_load_lds(
      (const __attribute__((address_space(1))) void*)g,
      (__attribute__((address_space(3))) void*)l, 16, 0, 0);
}

template<int N> __device__ __forceinline__ void vmcnt_wait() {
  if constexpr (N == 0)      asm volatile("s_waitcnt vmcnt(0)" ::: "memory");
  else if constexpr (N == 3) asm volatile("s_waitcnt vmcnt(3)" ::: "memory");
  else if constexpr (N == 4) asm volatile("s_waitcnt vmcnt(4)" ::: "memory");
  else if constexpr (N == 6) asm volatile("s_waitcnt vmcnt(6)" ::: "memory");
  else                       asm volatile("s_waitcnt vmcnt(8)" ::: "memory");
}

// ---------------- prep kernels (consolidated) ----------------

// gate (softmax over 8 experts) + tg aug columns (layer-invariant, written once)
__global__ void gate_aug_kernel(const int* __restrict__ dom, const float* __restrict__ emb,
                                const float* __restrict__ gW, const float* __restrict__ gb,
                                float* __restrict__ gate, unsigned short* __restrict__ tg) {
  int i = blockIdx.x * blockDim.x + threadIdx.x;
  int d = dom[i];
  float e0 = emb[d*4+0], e1 = emb[d*4+1], e2 = emb[d*4+2], e3 = emb[d*4+3];
  float l[8]; float mx = -1e30f;
#pragma unroll
  for (int j = 0; j < 8; j++) {
    l[j] = e0*gW[j] + e1*gW[8+j] + e2*gW[16+j] + e3*gW[24+j] + gb[j];
    mx = fmaxf(mx, l[j]);
  }
  float s = 0.f;
#pragma unroll
  for (int j = 0; j < 8; j++) { l[j] = __expf(l[j] - mx); s += l[j]; }
  float inv = 1.0f / s;
  unsigned int g[4];
#pragma unroll
  for (int j = 0; j < 8; j++) {
    float v = l[j] * inv;
    gate[i*8+j] = v;
    unsigned int b = f2b(v);
    if (j & 1) g[j >> 1] |= b << 16; else g[j >> 1] = b;
  }
  // aug: cols 128..191 (gate in 128..135, zeros after); 8 x uint4 per row
  uint4* dst = (uint4*)&tg[(long)i * KAUG + 128];
  dst[0] = make_uint4(g[0], g[1], g[2], g[3]);
  uint4 z4 = make_uint4(0, 0, 0, 0);
#pragma unroll
  for (int q = 1; q < 8; q++) dst[q] = z4;
}

__global__ void f32_to_bf16_vec(const float* __restrict__ in, unsigned int* __restrict__ out, long n8) {
  long i = (long)blockIdx.x * blockDim.x + threadIdx.x;
  if (i >= n8) return;
  float4 a = ((const float4*)in)[i * 2];
  float4 b = ((const float4*)in)[i * 2 + 1];
  uint4 o;
  o.x = f2b(a.x) | ((unsigned)f2b(a.y) << 16);
  o.y = f2b(a.z) | ((unsigned)f2b(a.w) << 16);
  o.z = f2b(b.x) | ((unsigned)f2b(b.y) << 16);
  o.w = f2b(b.z) | ((unsigned)f2b(b.w) << 16);
  ((uint4*)out)[i] = o;
}

// All three W transposes in one launch (z = layer). Wt[n*K+k] = bf16(W[k*N+n]).
__global__ void build_wt_all(const float* __restrict__ w0, const float* __restrict__ w1,
                             const float* __restrict__ w2,
                             unsigned short* __restrict__ t0, unsigned short* __restrict__ t1,
                             unsigned short* __restrict__ t2) {
  int z = blockIdx.z;
  const float* W = z == 0 ? w0 : (z == 1 ? w1 : w2);
  unsigned short* Wt = z == 0 ? t0 : (z == 1 ? t1 : t2);
  int K = (z == 2) ? 512 : 1024;
  int N = (z == 0) ? 1024 : (z == 1 ? 512 : 256);
  int n0 = blockIdx.x * 32, k0 = blockIdx.y * 32;
  if (n0 >= N || k0 >= K) return;
  __shared__ float tl[32][33];
  int tx = threadIdx.x & 31, ty = threadIdx.x >> 5;
#pragma unroll
  for (int i = 0; i < 32; i += 8)
    tl[ty + i][tx] = W[(long)(k0 + ty + i) * N + n0 + tx];
  __syncthreads();
#pragma unroll
  for (int i = 0; i < 32; i += 8)
    Wt[(long)(n0 + ty + i) * K + k0 + tx] = f2b(tl[tx][ty + i]);
}

// All three A transposes. Aft[(e*16+r)*P + p] = bf16(A[e][p][r]).
__global__ void build_aft_all(const float* __restrict__ a0, const float* __restrict__ a1,
                              const float* __restrict__ a2,
                              unsigned short* __restrict__ t0, unsigned short* __restrict__ t1,
                              unsigned short* __restrict__ t2) {
  int z = blockIdx.z;
  const float* A = z == 0 ? a0 : (z == 1 ? a1 : a2);
  unsigned short* Aft = z == 0 ? t0 : (z == 1 ? t1 : t2);
  int P = (z == 2) ? 512 : 1024;
  long p0 = (long)blockIdx.x * 64;
  if (p0 >= P) return;
  int e = blockIdx.y;
  __shared__ float tl[64][17];
  int t = threadIdx.x;
#pragma unroll
  for (int pass = 0; pass < 4; pass++) {
    int idx = t + pass * 256;
    int pl = idx >> 4, r = idx & 15;
    tl[pl][r] = A[((long)e * P + p0 + pl) * 16 + r];
  }
  __syncthreads();
#pragma unroll
  for (int pass = 0; pass < 4; pass++) {
    int idx = t + pass * 256;
    int r = idx >> 6, pl = idx & 63;
    Aft[(long)(e * 16 + r) * P + p0 + pl] = f2b(tl[pl][r]);
  }
}

// All three B-aug transposes. Bft[n*KAUG+kk]: kk<128 -> B[kk*H+n];
// kk in [128,136) -> lb[kk-128][n]; else 0.
__global__ void build_bft_all(const float* __restrict__ b0, const float* __restrict__ b1,
                              const float* __restrict__ b2,
                              const float* __restrict__ l0, const float* __restrict__ l1,
                              const float* __restrict__ l2,
                              unsigned short* __restrict__ t0, unsigned short* __restrict__ t1,
                              unsigned short* __restrict__ t2) {
  int z = blockIdx.z;
  const float* Bm = z == 0 ? b0 : (z == 1 ? b1 : b2);
  const float* lb = z == 0 ? l0 : (z == 1 ? l1 : l2);
  unsigned short* Bft = z == 0 ? t0 : (z == 1 ? t1 : t2);
  int H = (z == 0) ? 1024 : (z == 1 ? 512 : 256);
  int n0 = blockIdx.x * 32, kk0 = blockIdx.y * 32;
  if (n0 >= H) return;
  __shared__ float tl[32][33];
  int tx = threadIdx.x & 31, ty = threadIdx.x >> 5;
#pragma unroll
  for (int i = 0; i < 32; i += 8) {
    int kk = kk0 + ty + i;
    float v;
    if (kk < 128)       v = Bm[(long)kk * H + n0 + tx];
    else if (kk < 136)  v = lb[(long)(kk - 128) * H + n0 + tx];
    else                v = 0.f;
    tl[ty + i][tx] = v;
  }
  __syncthreads();
#pragma unroll
  for (int i = 0; i < 32; i += 8)
    Bft[(long)(n0 + ty + i) * KAUG + kk0 + tx] = f2b(tl[tx][ty + i]);
}

// ---------------- fine-phase 128-wide GEMM (x@A) ----------------
// BM x 128 tile, BK=64, 512 threads = 8 waves (2M x 4N), 3 LDS buffers,
// tile t+2 staged during tile t; counted vmcnt, never 0 in-loop.
template<int MODE, int BM>
__global__ __launch_bounds__(512)
void gemm_mn(const unsigned short* __restrict__ A1, int lda1, int K1,
             const unsigned short* __restrict__ A2, int lda2, int K2,
             const unsigned short* __restrict__ Bt1, int ldb1,
             const unsigned short* __restrict__ Bt2, int ldb2,
             const float* __restrict__ bias,
             const float* __restrict__ gate,
             void* __restrict__ outp, int ldout) {
  constexpr int MFRAG = BM / 32;
  constexpr int ATOT = BM * 64;
  constexpr int BTOT = 128 * 64;
  constexpr int LA = BM / 64;
  constexpr int L = LA + 2;
  __shared__ __attribute__((aligned(16))) unsigned short lds[3 * ATOT + 3 * BTOT];

  const int t = threadIdx.x;
  const int lane = t & 63, wave = t >> 6;
  const int wr = wave >> 2, wc = wave & 3;
  const int rl = lane & 15, kg = lane >> 4;
  const int row0 = blockIdx.x * BM, col0 = blockIdx.y * 128;

  const int sr = t >> 3;
  const int sk = ((t & 7) ^ (sr & 7)) * 8;

  f32x4 acc[MFRAG][2];
#pragma unroll
  for (int m = 0; m < MFRAG; m++)
#pragma unroll
    for (int n = 0; n < 2; n++) acc[m][n] = (f32x4){0.f, 0.f, 0.f, 0.f};

  auto stageA = [&](int buf, int kt) {
    const unsigned short* src; long ld; int kl;
    if (kt < K1) { src = A1; ld = lda1; kl = kt; }
    else         { src = A2; ld = lda2; kl = kt - K1; }
    unsigned short* d = &lds[buf * ATOT + t * 8];
    const unsigned short* s = src + (long)(row0 + sr) * ld + kl + sk;
#pragma unroll
    for (int i = 0; i < LA; i++)
      lds_load16(s + (long)(i * 64) * ld, d + i * 4096);
  };
  auto stageB = [&](int buf, int kt) {
    const unsigned short* src; long ld; int kl;
    if (kt < K1) { src = Bt1; ld = ldb1; kl = kt; }
    else         { src = Bt2; ld = ldb2; kl = kt - K1; }
    unsigned short* d = &lds[3 * ATOT + buf * BTOT + t * 8];
    const unsigned short* s = src + (long)(col0 + sr) * ld + kl + sk;
    lds_load16(s, d);
    lds_load16(s + 64 * ld, d + 4096);
  };
  auto ldA = [&](int buf, int mg, int ks) {
    int lr = wr * (BM / 2) + mg * 16 + rl;
    int sc = (ks * 4 + kg) ^ (lr & 7);
    return *(const bf16x8*)&lds[buf * ATOT + lr * 64 + sc * 8];
  };
  auto ldB = [&](int buf, int n, int ks) {
    int cr = wc * 32 + n * 16 + rl;
    int sc = (ks * 4 + kg) ^ (cr & 7);
    return *(const bf16x8*)&lds[3 * ATOT + buf * BTOT + cr * 64 + sc * 8];
  };

  const int Ktot = K1 + K2;
  const int NT = Ktot / 64;

  stageA(0, 0); stageB(0, 0);
  stageA(1, 64); stageB(1, 64);
  vmcnt_wait<L>();
  __builtin_amdgcn_s_barrier();

  int bcur = 0;
  bf16x8 Bfv[2][2];
  for (int tt = 0; tt < NT; ++tt) {
    int bpf = bcur + 2; if (bpf > 2) bpf -= 3;
    const bool pf = (tt + 2 < NT);
    bf16x8 Af[(MFRAG + 1) / 2][2];
#pragma unroll
    for (int m = 0; m < MFRAG / 2; m++) { Af[m][0] = ldA(bcur, m, 0); Af[m][1] = ldA(bcur, m, 1); }
#pragma unroll
    for (int n = 0; n < 2; n++) { Bfv[n][0] = ldB(bcur, n, 0); Bfv[n][1] = ldB(bcur, n, 1); }
    if (pf) stageA(bpf, (tt + 2) * 64);
    __builtin_amdgcn_s_barrier();
    asm volatile("s_waitcnt lgkmcnt(0)" ::: "memory");
    __builtin_amdgcn_sched_barrier(0);
    __builtin_amdgcn_s_setprio(1);
#pragma unroll
    for (int m = 0; m < MFRAG / 2; m++)
#pragma unroll
      for (int n = 0; n < 2; n++) {
        acc[m][n] = __builtin_amdgcn_mfma_f32_16x16x32_bf16(Af[m][0], Bfv[n][0], acc[m][n], 0, 0, 0);
        acc[m][n] = __builtin_amdgcn_mfma_f32_16x16x32_bf16(Af[m][1], Bfv[n][1], acc[m][n], 0, 0, 0);
      }
    __builtin_amdgcn_s_setprio(0);
    __builtin_amdgcn_s_barrier();
#pragma unroll
    for (int m = 0; m < MFRAG / 2; m++) { Af[m][0] = ldA(bcur, MFRAG / 2 + m, 0); Af[m][1] = ldA(bcur, MFRAG / 2 + m, 1); }
    if (pf) stageB(bpf, (tt + 2) * 64);
    if (tt + 1 < NT) vmcnt_wait<L>();
    else             vmcnt_wait<0>();
    __builtin_amdgcn_s_barrier();
    asm volatile("s_waitcnt lgkmcnt(0)" ::: "memory");
    __builtin_amdgcn_sched_barrier(0);
    __builtin_amdgcn_s_setprio(1);
#pragma unroll
    for (int m = 0; m < MFRAG / 2; m++)
#pragma unroll
      for (int n = 0; n < 2; n++) {
        acc[MFRAG / 2 + m][n] = __builtin_amdgcn_mfma_f32_16x16x32_bf16(Af[m][0], Bfv[n][0], acc[MFRAG / 2 + m][n], 0, 0, 0);
        acc[MFRAG / 2 + m][n] = __builtin_amdgcn_mfma_f32_16x16x32_bf16(Af[m][1], Bfv[n][1], acc[MFRAG / 2 + m][n], 0, 0, 0);
      }
    __builtin_amdgcn_s_setprio(0);
    __builtin_amdgcn_s_barrier();
    bcur = bcur == 2 ? 0 : bcur + 1;
  }

#pragma unroll
  for (int m = 0; m < MFRAG; m++)
#pragma unroll
    for (int n = 0; n < 2; n++)
#pragma unroll
      for (int j = 0; j < 4; j++) {
        int row = row0 + wr * (BM / 2) + m * 16 + kg * 4 + j;
        int col = col0 + wc * 32 + n * 16 + rl;
        float v = acc[m][n][j];
        if (MODE == 0) {
          v *= gate[row * 8 + (col >> 4)];
          ((unsigned short*)outp)[(long)row * ldout + col] = f2b(v);
        } else {
          v += bias[col];
          v = fmaxf(v, 0.f);
          if (MODE == 1) ((unsigned short*)outp)[(long)row * ldout + col] = f2b(v);
          else           ((float*)outp)[(long)row * ldout + col] = v;
        }
      }
}

// ---------------- gemm2b (main GEMMs): BK=64, 2 buffers, 2 blocks/CU ----------------
// BM x 128 tile, 256 threads = 4 waves (2M x 2N), per-wave BM/2 x 64.
// m97-mode scheduling: issue next tile's global_load_lds FIRST, then plain
// C++ ds_reads + MFMA (NO lgkmcnt(0)/sched_barrier pinning -- compiler emits
// fine-grained lgkmcnt so MFMA starts after the first fragment lands), then
// one __syncthreads() per K-tile. launch_bounds(256,2): LDS caps occupancy
// at 2 blocks/CU, so give the scheduler the full VGPR budget.
// Swizzle: 16B chunk c of row r at c^(r&7), both-sides.
template<int MODE, int BM>
__global__ __launch_bounds__(256, 2)
void gemm2b(const unsigned short* __restrict__ A1, int lda1, int K1,
            const unsigned short* __restrict__ A2, int lda2, int K2,
            const unsigned short* __restrict__ Bt1, int ldb1,
            const unsigned short* __restrict__ Bt2, int ldb2,
            const float* __restrict__ bias,
            const float* __restrict__ gate,
            void* __restrict__ outp, int ldout) {
  constexpr int ATOT = BM * 64;
  constexpr int BTOT = 128 * 64;
  constexpr int MF = BM / 64;
  constexpr int LA = BM / 32;
  __shared__ __attribute__((aligned(16))) unsigned short lds[2 * ATOT + 2 * BTOT];

  const int t = threadIdx.x;
  const int lane = t & 63, wave = t >> 6;
  const int wr = wave >> 1, wc = wave & 1;
  const int rl = lane & 15, kg = lane >> 4;
  const int row0 = blockIdx.x * BM, col0 = blockIdx.y * 128;

  const int sr = t >> 3;
  const int sk = ((t & 7) ^ (sr & 7)) * 8;

  f32x4 acc[2 * MF][4];
#pragma unroll
  for (int m = 0; m < 2 * MF; m++)
#pragma unroll
    for (int n = 0; n < 4; n++) acc[m][n] = (f32x4){0.f, 0.f, 0.f, 0.f};

  auto stageA = [&](int buf, int kt) {
    const unsigned short* src; long ld; int kl;
    if (kt < K1) { src = A1; ld = lda1; kl = kt; }
    else         { src = A2; ld = lda2; kl = kt - K1; }
    unsigned short* d = &lds[buf * ATOT + t * 8];
    const unsigned short* s = src + (long)(row0 + sr) * ld + kl + sk;
#pragma unroll
    for (int i = 0; i < LA; i++)
      lds_load16(s + (long)(i * 32) * ld, d + i * 2048);
  };
  auto stageB = [&](int buf, int kt) {
    const unsigned short* src; long ld; int kl;
    if (kt < K1) { src = Bt1; ld = ldb1; kl = kt; }
    else         { src = Bt2; ld = ldb2; kl = kt - K1; }
    unsigned short* d = &lds[2 * ATOT + buf * BTOT + t * 8];
    const unsigned short* s = src + (long)(col0 + sr) * ld + kl + sk;
#pragma unroll
    for (int i = 0; i < 4; i++)
      lds_load16(s + (long)(i * 32) * ld, d + i * 2048);
  };
  auto ldA = [&](int buf, int mf, int ks) {
    int lr = wr * (BM / 2) + mf * 16 + rl;
    int sc = (ks * 4 + kg) ^ (lr & 7);
    return *(const bf16x8*)&lds[buf * ATOT + lr * 64 + sc * 8];
  };
  auto ldB = [&](int buf, int nf, int ks) {
    int cr = wc * 64 + nf * 16 + rl;
    int sc = (ks * 4 + kg) ^ (cr & 7);
    return *(const bf16x8*)&lds[2 * ATOT + buf * BTOT + cr * 64 + sc * 8];
  };

  const int NT = (K1 + K2) / 64;

  stageA(0, 0); stageB(0, 0);
  __syncthreads();

  int cur = 0;
  for (int tt = 0; tt < NT; ++tt) {
    const bool pf = (tt + 1 < NT);
    const int kt1 = (tt + 1) * 64;
    if (pf) { stageA(cur ^ 1, kt1); stageB(cur ^ 1, kt1); }
    // phase 0: m-half 0, all n (compiler interleaves reads and MFMA)
    bf16x8 Am_[MF][2], Bf[4][2];
#pragma unroll
    for (int mf = 0; mf < MF; mf++) { Am_[mf][0] = ldA(cur, mf, 0); Am_[mf][1] = ldA(cur, mf, 1); }
#pragma unroll
    for (int nf = 0; nf < 4; nf++) { Bf[nf][0] = ldB(cur, nf, 0); Bf[nf][1] = ldB(cur, nf, 1); }
#pragma unroll
    for (int mf = 0; mf < MF; mf++)
#pragma unroll
      for (int nf = 0; nf < 4; nf++) {
        acc[mf][nf] = __builtin_amdgcn_mfma_f32_16x16x32_bf16(Am_[mf][0], Bf[nf][0], acc[mf][nf], 0, 0, 0);
        acc[mf][nf] = __builtin_amdgcn_mfma_f32_16x16x32_bf16(Am_[mf][1], Bf[nf][1], acc[mf][nf], 0, 0, 0);
      }
    // phase 1: m-half 1, all n (B reused from regs)
#pragma unroll
    for (int mf = 0; mf < MF; mf++) { Am_[mf][0] = ldA(cur, MF + mf, 0); Am_[mf][1] = ldA(cur, MF + mf, 1); }
#pragma unroll
    for (int mf = 0; mf < MF; mf++)
#pragma unroll
      for (int nf = 0; nf < 4; nf++) {
        acc[MF + mf][nf] = __builtin_amdgcn_mfma_f32_16x16x32_bf16(Am_[mf][0], Bf[nf][0], acc[MF + mf][nf], 0, 0, 0);
        acc[MF + mf][nf] = __builtin_amdgcn_mfma_f32_16x16x32_bf16(Am_[mf][1], Bf[nf][1], acc[MF + mf][nf], 0, 0, 0);
      }
    __syncthreads();   // vmcnt(0)+lgkmcnt(0)+barrier: next tile resident
    cur ^= 1;
  }

#pragma unroll
  for (int m = 0; m < 2 * MF; m++)
#pragma unroll
    for (int n = 0; n < 4; n++)
#pragma unroll
      for (int j = 0; j < 4; j++) {
        int row = row0 + wr * (BM / 2) + m * 16 + kg * 4 + j;
        int col = col0 + wc * 64 + n * 16 + rl;
        float v = acc[m][n][j];
        if (MODE == 0) {
          v *= gate[row * 8 + (col >> 4)];
          ((unsigned short*)outp)[(long)row * ldout + col] = f2b(v);
        } else {
          v += bias[col];
          v = fmaxf(v, 0.f);
          if (MODE == 1) ((unsigned short*)outp)[(long)row * ldout + col] = f2b(v);
          else           ((float*)outp)[(long)row * ldout + col] = v;
        }
      }
}

// ---------------- launch ----------------

extern "C" void kernel_launch(void* const* d_in, const int* in_sizes, int n_in,
                              void* d_out, int out_size, void* d_ws, size_t ws_size,
                              hipStream_t stream) {
  (void)in_sizes; (void)n_in; (void)out_size; (void)ws_size;
  const float* dnn = (const float*)d_in[0];
  const int*   dom = (const int*)d_in[1];
  const float* emb = (const float*)d_in[2];
  const float* gW  = (const float*)d_in[3];
  const float* gb  = (const float*)d_in[4];
  const float* Wm[3]  = {(const float*)d_in[5],  (const float*)d_in[10], (const float*)d_in[15]};
  const float* bm[3]  = {(const float*)d_in[6],  (const float*)d_in[11], (const float*)d_in[16]};
  const float* Am[3]  = {(const float*)d_in[7],  (const float*)d_in[12], (const float*)d_in[17]};
  const float* Bm[3]  = {(const float*)d_in[8],  (const float*)d_in[13], (const float*)d_in[18]};
  const float* lbm[3] = {(const float*)d_in[9],  (const float*)d_in[14], (const float*)d_in[19]};

  const int M = M_ROWS;
  const int dIn[3]  = {1024, 1024, 512};
  const int dOutN[3] = {1024, 512, 256};

  char* p = (char*)d_ws;
  auto carve = [&](size_t bytes) { char* r = p; p += (bytes + 255) & ~(size_t)255; return r; };
  float* gate = (float*)carve((size_t)M * 8 * sizeof(float));
  unsigned short* xb0 = (unsigned short*)carve((size_t)M * 1024 * 2);
  unsigned short* xb1 = (unsigned short*)carve((size_t)M * 1024 * 2);
  unsigned short* tg  = (unsigned short*)carve((size_t)M * KAUG * 2);
  unsigned short *Wt[3], *Aft[3], *Bft[3];
  for (int l = 0; l < 3; l++) {
    Wt[l]  = (unsigned short*)carve((size_t)dOutN[l] * dIn[l] * 2);
    Aft[l] = (unsigned short*)carve((size_t)128 * dIn[l] * 2);
    Bft[l] = (unsigned short*)carve((size_t)dOutN[l] * KAUG * 2);
  }

  gate_aug_kernel<<<M / 256, 256, 0, stream>>>(dom, emb, gW, gb, gate, tg);
  {
    long n8 = (long)M * 1024 / 8;
    f32_to_bf16_vec<<<(int)((n8 + 255) / 256), 256, 0, stream>>>(dnn, (unsigned int*)xb0, n8);
  }
  build_wt_all<<<dim3(32, 32, 3), 256, 0, stream>>>(Wm[0], Wm[1], Wm[2], Wt[0], Wt[1], Wt[2]);
  build_aft_all<<<dim3(16, 8, 3), 256, 0, stream>>>(Am[0], Am[1], Am[2], Aft[0], Aft[1], Aft[2]);
  build_bft_all<<<dim3(32, KAUG / 32, 3), 256, 0, stream>>>(Bm[0], Bm[1], Bm[2],
                                                            lbm[0], lbm[1], lbm[2],
                                                            Bft[0], Bft[1], Bft[2]);

  const unsigned short* xin = xb0;
  for (int l = 0; l < 3; l++) {
    int K1 = dIn[l], N = dOutN[l];
    // tg[:, :128] = gate-scaled x @ A_flat  (deep-pipelined, 256 blocks)
    gemm_mn<0, 64><<<dim3(M / 64, 1), 512, 0, stream>>>(
        xin, K1, K1, nullptr, 0, 0, Aft[l], K1, nullptr, 0, nullptr, gate, (void*)tg, KAUG);
    // out = relu(x @ W + tg_aug @ B_aug + bias)
    if (l == 0)
      gemm2b<1, 128><<<dim3(M / 128, N / 128), 256, 0, stream>>>(
          xin, K1, K1, tg, KAUG, KAUG, Wt[l], K1, Bft[l], KAUG, bm[l], nullptr, (void*)xb1, N);
    else if (l == 1)
      gemm2b<1, 128><<<dim3(M / 128, N / 128), 256, 0, stream>>>(
          xin, K1, K1, tg, KAUG, KAUG, Wt[l], K1, Bft[l], KAUG, bm[l], nullptr, (void*)xb0, N);
    else
      gemm2b<2, 64><<<dim3(M / 64, N / 128), 256, 0, stream>>>(
          xin, K1, K1, tg, KAUG, KAUG, Wt[l], K1, Bft[l], KAUG, bm[l], nullptr, d_out, N);
    xin = (l == 0) ? xb1 : xb0;
  }
}

// Round 17
// 139.732 us; speedup vs baseline: 1.0209x; 1.0209x over previous
//
#include <hip/hip_runtime.h>
#include <hip/hip_bf16.h>
#include <stdint.h>

#define KAUG 192   // 128 LoRA cols + 8 gate cols + 56 zero pad (multiple of 64)
#define M_ROWS 16384

typedef __attribute__((ext_vector_type(8))) __bf16 bf16x8;
typedef __attribute__((ext_vector_type(4))) float f32x4;

__device__ __forceinline__ unsigned short f2b(float f) {
  unsigned int u = __builtin_bit_cast(unsigned int, f);
  u = (u + 0x7fffu + ((u >> 16) & 1u)) >> 16;
  return (unsigned short)u;
}

__device__ __forceinline__ void lds_load16(const unsigned short* g, unsigned short* l) {
  __builtin_amdgcn_global_load_lds(
      (const __attribute__((address_space(1))) void*)g,
      (__attribute__((address_space(3))) void*)l, 16, 0, 0);
}

template<int N> __device__ __forceinline__ void vmcnt_wait() {
  if constexpr (N == 0)      asm volatile("s_waitcnt vmcnt(0)" ::: "memory");
  else if constexpr (N == 3) asm volatile("s_waitcnt vmcnt(3)" ::: "memory");
  else if constexpr (N == 4) asm volatile("s_waitcnt vmcnt(4)" ::: "memory");
  else if constexpr (N == 6) asm volatile("s_waitcnt vmcnt(6)" ::: "memory");
  else                       asm volatile("s_waitcnt vmcnt(8)" ::: "memory");
}

// ---------------- prep kernels (consolidated) ----------------

// gate (softmax over 8 experts) + tg aug columns (layer-invariant, written once)
__global__ void gate_aug_kernel(const int* __restrict__ dom, const float* __restrict__ emb,
                                const float* __restrict__ gW, const float* __restrict__ gb,
                                float* __restrict__ gate, unsigned short* __restrict__ tg) {
  int i = blockIdx.x * blockDim.x + threadIdx.x;
  int d = dom[i];
  float e0 = emb[d*4+0], e1 = emb[d*4+1], e2 = emb[d*4+2], e3 = emb[d*4+3];
  float l[8]; float mx = -1e30f;
#pragma unroll
  for (int j = 0; j < 8; j++) {
    l[j] = e0*gW[j] + e1*gW[8+j] + e2*gW[16+j] + e3*gW[24+j] + gb[j];
    mx = fmaxf(mx, l[j]);
  }
  float s = 0.f;
#pragma unroll
  for (int j = 0; j < 8; j++) { l[j] = __expf(l[j] - mx); s += l[j]; }
  float inv = 1.0f / s;
  unsigned int g[4];
#pragma unroll
  for (int j = 0; j < 8; j++) {
    float v = l[j] * inv;
    gate[i*8+j] = v;
    unsigned int b = f2b(v);
    if (j & 1) g[j >> 1] |= b << 16; else g[j >> 1] = b;
  }
  // aug: cols 128..191 (gate in 128..135, zeros after); 8 x uint4 per row
  uint4* dst = (uint4*)&tg[(long)i * KAUG + 128];
  dst[0] = make_uint4(g[0], g[1], g[2], g[3]);
  uint4 z4 = make_uint4(0, 0, 0, 0);
#pragma unroll
  for (int q = 1; q < 8; q++) dst[q] = z4;
}

__global__ void f32_to_bf16_vec(const float* __restrict__ in, unsigned int* __restrict__ out, long n8) {
  long i = (long)blockIdx.x * blockDim.x + threadIdx.x;
  if (i >= n8) return;
  float4 a = ((const float4*)in)[i * 2];
  float4 b = ((const float4*)in)[i * 2 + 1];
  uint4 o;
  o.x = f2b(a.x) | ((unsigned)f2b(a.y) << 16);
  o.y = f2b(a.z) | ((unsigned)f2b(a.w) << 16);
  o.z = f2b(b.x) | ((unsigned)f2b(b.y) << 16);
  o.w = f2b(b.z) | ((unsigned)f2b(b.w) << 16);
  ((uint4*)out)[i] = o;
}

// All three W transposes in one launch (z = layer). Wt[n*K+k] = bf16(W[k*N+n]).
__global__ void build_wt_all(const float* __restrict__ w0, const float* __restrict__ w1,
                             const float* __restrict__ w2,
                             unsigned short* __restrict__ t0, unsigned short* __restrict__ t1,
                             unsigned short* __restrict__ t2) {
  int z = blockIdx.z;
  const float* W = z == 0 ? w0 : (z == 1 ? w1 : w2);
  unsigned short* Wt = z == 0 ? t0 : (z == 1 ? t1 : t2);
  int K = (z == 2) ? 512 : 1024;
  int N = (z == 0) ? 1024 : (z == 1 ? 512 : 256);
  int n0 = blockIdx.x * 32, k0 = blockIdx.y * 32;
  if (n0 >= N || k0 >= K) return;
  __shared__ float tl[32][33];
  int tx = threadIdx.x & 31, ty = threadIdx.x >> 5;
#pragma unroll
  for (int i = 0; i < 32; i += 8)
    tl[ty + i][tx] = W[(long)(k0 + ty + i) * N + n0 + tx];
  __syncthreads();
#pragma unroll
  for (int i = 0; i < 32; i += 8)
    Wt[(long)(n0 + ty + i) * K + k0 + tx] = f2b(tl[tx][ty + i]);
}

// All three A transposes. Aft[(e*16+r)*P + p] = bf16(A[e][p][r]).
__global__ void build_aft_all(const float* __restrict__ a0, const float* __restrict__ a1,
                              const float* __restrict__ a2,
                              unsigned short* __restrict__ t0, unsigned short* __restrict__ t1,
                              unsigned short* __restrict__ t2) {
  int z = blockIdx.z;
  const float* A = z == 0 ? a0 : (z == 1 ? a1 : a2);
  unsigned short* Aft = z == 0 ? t0 : (z == 1 ? t1 : t2);
  int P = (z == 2) ? 512 : 1024;
  long p0 = (long)blockIdx.x * 64;
  if (p0 >= P) return;
  int e = blockIdx.y;
  __shared__ float tl[64][17];
  int t = threadIdx.x;
#pragma unroll
  for (int pass = 0; pass < 4; pass++) {
    int idx = t + pass * 256;
    int pl = idx >> 4, r = idx & 15;
    tl[pl][r] = A[((long)e * P + p0 + pl) * 16 + r];
  }
  __syncthreads();
#pragma unroll
  for (int pass = 0; pass < 4; pass++) {
    int idx = t + pass * 256;
    int r = idx >> 6, pl = idx & 63;
    Aft[(long)(e * 16 + r) * P + p0 + pl] = f2b(tl[pl][r]);
  }
}

// All three B-aug transposes. Bft[n*KAUG+kk]: kk<128 -> B[kk*H+n];
// kk in [128,136) -> lb[kk-128][n]; else 0.
__global__ void build_bft_all(const float* __restrict__ b0, const float* __restrict__ b1,
                              const float* __restrict__ b2,
                              const float* __restrict__ l0, const float* __restrict__ l1,
                              const float* __restrict__ l2,
                              unsigned short* __restrict__ t0, unsigned short* __restrict__ t1,
                              unsigned short* __restrict__ t2) {
  int z = blockIdx.z;
  const float* Bm = z == 0 ? b0 : (z == 1 ? b1 : b2);
  const float* lb = z == 0 ? l0 : (z == 1 ? l1 : l2);
  unsigned short* Bft = z == 0 ? t0 : (z == 1 ? t1 : t2);
  int H = (z == 0) ? 1024 : (z == 1 ? 512 : 256);
  int n0 = blockIdx.x * 32, kk0 = blockIdx.y * 32;
  if (n0 >= H) return;
  __shared__ float tl[32][33];
  int tx = threadIdx.x & 31, ty = threadIdx.x >> 5;
#pragma unroll
  for (int i = 0; i < 32; i += 8) {
    int kk = kk0 + ty + i;
    float v;
    if (kk < 128)       v = Bm[(long)kk * H + n0 + tx];
    else if (kk < 136)  v = lb[(long)(kk - 128) * H + n0 + tx];
    else                v = 0.f;
    tl[ty + i][tx] = v;
  }
  __syncthreads();
#pragma unroll
  for (int i = 0; i < 32; i += 8)
    Bft[(long)(n0 + ty + i) * KAUG + kk0 + tx] = f2b(tl[tx][ty + i]);
}

// ---------------- fine-phase 128-wide GEMM (x@A) ----------------
// BM x 128 tile, BK=64, 512 threads = 8 waves (2M x 4N), 3 LDS buffers,
// tile t+2 staged during tile t; counted vmcnt, never 0 in-loop.
template<int MODE, int BM>
__global__ __launch_bounds__(512)
void gemm_mn(const unsigned short* __restrict__ A1, int lda1, int K1,
             const unsigned short* __restrict__ A2, int lda2, int K2,
             const unsigned short* __restrict__ Bt1, int ldb1,
             const unsigned short* __restrict__ Bt2, int ldb2,
             const float* __restrict__ bias,
             const float* __restrict__ gate,
             void* __restrict__ outp, int ldout) {
  constexpr int MFRAG = BM / 32;
  constexpr int ATOT = BM * 64;
  constexpr int BTOT = 128 * 64;
  constexpr int LA = BM / 64;
  constexpr int L = LA + 2;
  __shared__ __attribute__((aligned(16))) unsigned short lds[3 * ATOT + 3 * BTOT];

  const int t = threadIdx.x;
  const int lane = t & 63, wave = t >> 6;
  const int wr = wave >> 2, wc = wave & 3;
  const int rl = lane & 15, kg = lane >> 4;
  const int row0 = blockIdx.x * BM, col0 = blockIdx.y * 128;

  const int sr = t >> 3;
  const int sk = ((t & 7) ^ (sr & 7)) * 8;

  f32x4 acc[MFRAG][2];
#pragma unroll
  for (int m = 0; m < MFRAG; m++)
#pragma unroll
    for (int n = 0; n < 2; n++) acc[m][n] = (f32x4){0.f, 0.f, 0.f, 0.f};

  auto stageA = [&](int buf, int kt) {
    const unsigned short* src; long ld; int kl;
    if (kt < K1) { src = A1; ld = lda1; kl = kt; }
    else         { src = A2; ld = lda2; kl = kt - K1; }
    unsigned short* d = &lds[buf * ATOT + t * 8];
    const unsigned short* s = src + (long)(row0 + sr) * ld + kl + sk;
#pragma unroll
    for (int i = 0; i < LA; i++)
      lds_load16(s + (long)(i * 64) * ld, d + i * 4096);
  };
  auto stageB = [&](int buf, int kt) {
    const unsigned short* src; long ld; int kl;
    if (kt < K1) { src = Bt1; ld = ldb1; kl = kt; }
    else         { src = Bt2; ld = ldb2; kl = kt - K1; }
    unsigned short* d = &lds[3 * ATOT + buf * BTOT + t * 8];
    const unsigned short* s = src + (long)(col0 + sr) * ld + kl + sk;
    lds_load16(s, d);
    lds_load16(s + 64 * ld, d + 4096);
  };
  auto ldA = [&](int buf, int mg, int ks) {
    int lr = wr * (BM / 2) + mg * 16 + rl;
    int sc = (ks * 4 + kg) ^ (lr & 7);
    return *(const bf16x8*)&lds[buf * ATOT + lr * 64 + sc * 8];
  };
  auto ldB = [&](int buf, int n, int ks) {
    int cr = wc * 32 + n * 16 + rl;
    int sc = (ks * 4 + kg) ^ (cr & 7);
    return *(const bf16x8*)&lds[3 * ATOT + buf * BTOT + cr * 64 + sc * 8];
  };

  const int Ktot = K1 + K2;
  const int NT = Ktot / 64;

  stageA(0, 0); stageB(0, 0);
  stageA(1, 64); stageB(1, 64);
  vmcnt_wait<L>();
  __builtin_amdgcn_s_barrier();

  int bcur = 0;
  bf16x8 Bfv[2][2];
  for (int tt = 0; tt < NT; ++tt) {
    int bpf = bcur + 2; if (bpf > 2) bpf -= 3;
    const bool pf = (tt + 2 < NT);
    bf16x8 Af[(MFRAG + 1) / 2][2];
#pragma unroll
    for (int m = 0; m < MFRAG / 2; m++) { Af[m][0] = ldA(bcur, m, 0); Af[m][1] = ldA(bcur, m, 1); }
#pragma unroll
    for (int n = 0; n < 2; n++) { Bfv[n][0] = ldB(bcur, n, 0); Bfv[n][1] = ldB(bcur, n, 1); }
    if (pf) stageA(bpf, (tt + 2) * 64);
    __builtin_amdgcn_s_barrier();
    asm volatile("s_waitcnt lgkmcnt(0)" ::: "memory");
    __builtin_amdgcn_sched_barrier(0);
    __builtin_amdgcn_s_setprio(1);
#pragma unroll
    for (int m = 0; m < MFRAG / 2; m++)
#pragma unroll
      for (int n = 0; n < 2; n++) {
        acc[m][n] = __builtin_amdgcn_mfma_f32_16x16x32_bf16(Af[m][0], Bfv[n][0], acc[m][n], 0, 0, 0);
        acc[m][n] = __builtin_amdgcn_mfma_f32_16x16x32_bf16(Af[m][1], Bfv[n][1], acc[m][n], 0, 0, 0);
      }
    __builtin_amdgcn_s_setprio(0);
    __builtin_amdgcn_s_barrier();
#pragma unroll
    for (int m = 0; m < MFRAG / 2; m++) { Af[m][0] = ldA(bcur, MFRAG / 2 + m, 0); Af[m][1] = ldA(bcur, MFRAG / 2 + m, 1); }
    if (pf) stageB(bpf, (tt + 2) * 64);
    if (tt + 1 < NT) vmcnt_wait<L>();
    else             vmcnt_wait<0>();
    __builtin_amdgcn_s_barrier();
    asm volatile("s_waitcnt lgkmcnt(0)" ::: "memory");
    __builtin_amdgcn_sched_barrier(0);
    __builtin_amdgcn_s_setprio(1);
#pragma unroll
    for (int m = 0; m < MFRAG / 2; m++)
#pragma unroll
      for (int n = 0; n < 2; n++) {
        acc[MFRAG / 2 + m][n] = __builtin_amdgcn_mfma_f32_16x16x32_bf16(Af[m][0], Bfv[n][0], acc[MFRAG / 2 + m][n], 0, 0, 0);
        acc[MFRAG / 2 + m][n] = __builtin_amdgcn_mfma_f32_16x16x32_bf16(Af[m][1], Bfv[n][1], acc[MFRAG / 2 + m][n], 0, 0, 0);
      }
    __builtin_amdgcn_s_setprio(0);
    __builtin_amdgcn_s_barrier();
    bcur = bcur == 2 ? 0 : bcur + 1;
  }

#pragma unroll
  for (int m = 0; m < MFRAG; m++)
#pragma unroll
    for (int n = 0; n < 2; n++)
#pragma unroll
      for (int j = 0; j < 4; j++) {
        int row = row0 + wr * (BM / 2) + m * 16 + kg * 4 + j;
        int col = col0 + wc * 32 + n * 16 + rl;
        float v = acc[m][n][j];
        if (MODE == 0) {
          v *= gate[row * 8 + (col >> 4)];
          ((unsigned short*)outp)[(long)row * ldout + col] = f2b(v);
        } else {
          v += bias[col];
          v = fmaxf(v, 0.f);
          if (MODE == 1) ((unsigned short*)outp)[(long)row * ldout + col] = f2b(v);
          else           ((float*)outp)[(long)row * ldout + col] = v;
        }
      }
}

// ---------------- gemm2b (main GEMMs): BK=64, 2 buffers, 2 blocks/CU ----------------
// BM x 128 tile, 256 threads = 4 waves (2M x 2N), per-wave BM/2 x 64.
// Per K-tile: issue all prefetch gload_lds FIRST, then 2 {ds_read, lgkm0, MFMA}
// phases, then vmcnt(0) + ONE barrier per tile. Swizzle: chunk c of row r at c^(r&7).
template<int MODE, int BM>
__global__ __launch_bounds__(256, 4)
void gemm2b(const unsigned short* __restrict__ A1, int lda1, int K1,
            const unsigned short* __restrict__ A2, int lda2, int K2,
            const unsigned short* __restrict__ Bt1, int ldb1,
            const unsigned short* __restrict__ Bt2, int ldb2,
            const float* __restrict__ bias,
            const float* __restrict__ gate,
            void* __restrict__ outp, int ldout) {
  constexpr int ATOT = BM * 64;
  constexpr int BTOT = 128 * 64;
  constexpr int MF = BM / 64;
  constexpr int LA = BM / 32;
  __shared__ __attribute__((aligned(16))) unsigned short lds[2 * ATOT + 2 * BTOT];

  const int t = threadIdx.x;
  const int lane = t & 63, wave = t >> 6;
  const int wr = wave >> 1, wc = wave & 1;
  const int rl = lane & 15, kg = lane >> 4;
  const int row0 = blockIdx.x * BM, col0 = blockIdx.y * 128;

  const int sr = t >> 3;
  const int sk = ((t & 7) ^ (sr & 7)) * 8;

  f32x4 acc[2 * MF][4];
#pragma unroll
  for (int m = 0; m < 2 * MF; m++)
#pragma unroll
    for (int n = 0; n < 4; n++) acc[m][n] = (f32x4){0.f, 0.f, 0.f, 0.f};

  auto stageA = [&](int buf, int kt) {
    const unsigned short* src; long ld; int kl;
    if (kt < K1) { src = A1; ld = lda1; kl = kt; }
    else         { src = A2; ld = lda2; kl = kt - K1; }
    unsigned short* d = &lds[buf * ATOT + t * 8];
    const unsigned short* s = src + (long)(row0 + sr) * ld + kl + sk;
#pragma unroll
    for (int i = 0; i < LA; i++)
      lds_load16(s + (long)(i * 32) * ld, d + i * 2048);
  };
  auto stageB = [&](int buf, int kt) {
    const unsigned short* src; long ld; int kl;
    if (kt < K1) { src = Bt1; ld = ldb1; kl = kt; }
    else         { src = Bt2; ld = ldb2; kl = kt - K1; }
    unsigned short* d = &lds[2 * ATOT + buf * BTOT + t * 8];
    const unsigned short* s = src + (long)(col0 + sr) * ld + kl + sk;
#pragma unroll
    for (int i = 0; i < 4; i++)
      lds_load16(s + (long)(i * 32) * ld, d + i * 2048);
  };
  auto ldA = [&](int buf, int mf, int ks) {
    int lr = wr * (BM / 2) + mf * 16 + rl;
    int sc = (ks * 4 + kg) ^ (lr & 7);
    return *(const bf16x8*)&lds[buf * ATOT + lr * 64 + sc * 8];
  };
  auto ldB = [&](int buf, int nf, int ks) {
    int cr = wc * 64 + nf * 16 + rl;
    int sc = (ks * 4 + kg) ^ (cr & 7);
    return *(const bf16x8*)&lds[2 * ATOT + buf * BTOT + cr * 64 + sc * 8];
  };

  const int NT = (K1 + K2) / 64;

  stageA(0, 0); stageB(0, 0);
  asm volatile("s_waitcnt vmcnt(0)" ::: "memory");
  __builtin_amdgcn_s_barrier();

  int cur = 0;
  for (int tt = 0; tt < NT; ++tt) {
    const bool pf = (tt + 1 < NT);
    const int kt1 = (tt + 1) * 64;
    if (pf) { stageA(cur ^ 1, kt1); stageB(cur ^ 1, kt1); }
    bf16x8 Am_[MF][2], Bf[4][2];
#pragma unroll
    for (int mf = 0; mf < MF; mf++) { Am_[mf][0] = ldA(cur, mf, 0); Am_[mf][1] = ldA(cur, mf, 1); }
#pragma unroll
    for (int nf = 0; nf < 4; nf++) { Bf[nf][0] = ldB(cur, nf, 0); Bf[nf][1] = ldB(cur, nf, 1); }
    asm volatile("s_waitcnt lgkmcnt(0)" ::: "memory");
    __builtin_amdgcn_sched_barrier(0);
    __builtin_amdgcn_s_setprio(1);
#pragma unroll
    for (int mf = 0; mf < MF; mf++)
#pragma unroll
      for (int nf = 0; nf < 4; nf++) {
        acc[mf][nf] = __builtin_amdgcn_mfma_f32_16x16x32_bf16(Am_[mf][0], Bf[nf][0], acc[mf][nf], 0, 0, 0);
        acc[mf][nf] = __builtin_amdgcn_mfma_f32_16x16x32_bf16(Am_[mf][1], Bf[nf][1], acc[mf][nf], 0, 0, 0);
      }
    __builtin_amdgcn_s_setprio(0);
#pragma unroll
    for (int mf = 0; mf < MF; mf++) { Am_[mf][0] = ldA(cur, MF + mf, 0); Am_[mf][1] = ldA(cur, MF + mf, 1); }
    asm volatile("s_waitcnt lgkmcnt(0)" ::: "memory");
    __builtin_amdgcn_sched_barrier(0);
    __builtin_amdgcn_s_setprio(1);
#pragma unroll
    for (int mf = 0; mf < MF; mf++)
#pragma unroll
      for (int nf = 0; nf < 4; nf++) {
        acc[MF + mf][nf] = __builtin_amdgcn_mfma_f32_16x16x32_bf16(Am_[mf][0], Bf[nf][0], acc[MF + mf][nf], 0, 0, 0);
        acc[MF + mf][nf] = __builtin_amdgcn_mfma_f32_16x16x32_bf16(Am_[mf][1], Bf[nf][1], acc[MF + mf][nf], 0, 0, 0);
      }
    __builtin_amdgcn_s_setprio(0);
    if (pf) asm volatile("s_waitcnt vmcnt(0)" ::: "memory");
    __builtin_amdgcn_s_barrier();
    cur ^= 1;
  }

#pragma unroll
  for (int m = 0; m < 2 * MF; m++)
#pragma unroll
    for (int n = 0; n < 4; n++)
#pragma unroll
      for (int j = 0; j < 4; j++) {
        int row = row0 + wr * (BM / 2) + m * 16 + kg * 4 + j;
        int col = col0 + wc * 64 + n * 16 + rl;
        float v = acc[m][n][j];
        if (MODE == 0) {
          v *= gate[row * 8 + (col >> 4)];
          ((unsigned short*)outp)[(long)row * ldout + col] = f2b(v);
        } else {
          v += bias[col];
          v = fmaxf(v, 0.f);
          if (MODE == 1) ((unsigned short*)outp)[(long)row * ldout + col] = f2b(v);
          else           ((float*)outp)[(long)row * ldout + col] = v;
        }
      }
}

// ---------------- launch ----------------

extern "C" void kernel_launch(void* const* d_in, const int* in_sizes, int n_in,
                              void* d_out, int out_size, void* d_ws, size_t ws_size,
                              hipStream_t stream) {
  (void)in_sizes; (void)n_in; (void)out_size; (void)ws_size;
  const float* dnn = (const float*)d_in[0];
  const int*   dom = (const int*)d_in[1];
  const float* emb = (const float*)d_in[2];
  const float* gW  = (const float*)d_in[3];
  const float* gb  = (const float*)d_in[4];
  const float* Wm[3]  = {(const float*)d_in[5],  (const float*)d_in[10], (const float*)d_in[15]};
  const float* bm[3]  = {(const float*)d_in[6],  (const float*)d_in[11], (const float*)d_in[16]};
  const float* Am[3]  = {(const float*)d_in[7],  (const float*)d_in[12], (const float*)d_in[17]};
  const float* Bm[3]  = {(const float*)d_in[8],  (const float*)d_in[13], (const float*)d_in[18]};
  const float* lbm[3] = {(const float*)d_in[9],  (const float*)d_in[14], (const float*)d_in[19]};

  const int M = M_ROWS;
  const int dIn[3]  = {1024, 1024, 512};
  const int dOutN[3] = {1024, 512, 256};

  char* p = (char*)d_ws;
  auto carve = [&](size_t bytes) { char* r = p; p += (bytes + 255) & ~(size_t)255; return r; };
  float* gate = (float*)carve((size_t)M * 8 * sizeof(float));
  unsigned short* xb0 = (unsigned short*)carve((size_t)M * 1024 * 2);
  unsigned short* xb1 = (unsigned short*)carve((size_t)M * 1024 * 2);
  unsigned short* tg  = (unsigned short*)carve((size_t)M * KAUG * 2);
  unsigned short *Wt[3], *Aft[3], *Bft[3];
  for (int l = 0; l < 3; l++) {
    Wt[l]  = (unsigned short*)carve((size_t)dOutN[l] * dIn[l] * 2);
    Aft[l] = (unsigned short*)carve((size_t)128 * dIn[l] * 2);
    Bft[l] = (unsigned short*)carve((size_t)dOutN[l] * KAUG * 2);
  }

  gate_aug_kernel<<<M / 256, 256, 0, stream>>>(dom, emb, gW, gb, gate, tg);
  {
    long n8 = (long)M * 1024 / 8;
    f32_to_bf16_vec<<<(int)((n8 + 255) / 256), 256, 0, stream>>>(dnn, (unsigned int*)xb0, n8);
  }
  build_wt_all<<<dim3(32, 32, 3), 256, 0, stream>>>(Wm[0], Wm[1], Wm[2], Wt[0], Wt[1], Wt[2]);
  build_aft_all<<<dim3(16, 8, 3), 256, 0, stream>>>(Am[0], Am[1], Am[2], Aft[0], Aft[1], Aft[2]);
  build_bft_all<<<dim3(32, KAUG / 32, 3), 256, 0, stream>>>(Bm[0], Bm[1], Bm[2],
                                                            lbm[0], lbm[1], lbm[2],
                                                            Bft[0], Bft[1], Bft[2]);

  const unsigned short* xin = xb0;
  for (int l = 0; l < 3; l++) {
    int K1 = dIn[l], N = dOutN[l];
    // tg[:, :128] = gate-scaled x @ A_flat  (deep-pipelined, 256 blocks)
    gemm_mn<0, 64><<<dim3(M / 64, 1), 512, 0, stream>>>(
        xin, K1, K1, nullptr, 0, 0, Aft[l], K1, nullptr, 0, nullptr, gate, (void*)tg, KAUG);
    // out = relu(x @ W + tg_aug @ B_aug + bias)
    if (l == 0)
      gemm2b<1, 128><<<dim3(M / 128, N / 128), 256, 0, stream>>>(
          xin, K1, K1, tg, KAUG, KAUG, Wt[l], K1, Bft[l], KAUG, bm[l], nullptr, (void*)xb1, N);
    else if (l == 1)
      gemm2b<1, 128><<<dim3(M / 128, N / 128), 256, 0, stream>>>(
          xin, K1, K1, tg, KAUG, KAUG, Wt[l], K1, Bft[l], KAUG, bm[l], nullptr, (void*)xb0, N);
    else
      gemm2b<2, 64><<<dim3(M / 64, N / 128), 256, 0, stream>>>(
          xin, K1, K1, tg, KAUG, KAUG, Wt[l], K1, Bft[l], KAUG, bm[l], nullptr, d_out, N);
    xin = (l == 0) ? xb1 : xb0;
  }
}

// Round 18
// 132.229 us; speedup vs baseline: 1.0788x; 1.0567x over previous
//
#include <hip/hip_runtime.h>
#include <hip/hip_bf16.h>
#include <stdint.h>

#define KAUG 192   // 128 LoRA cols + 8 gate cols + 56 zero pad (multiple of 64)
#define M_ROWS 16384

typedef __attribute__((ext_vector_type(8))) __bf16 bf16x8;
typedef __attribute__((ext_vector_type(4))) float f32x4;

__device__ __forceinline__ unsigned short f2b(float f) {
  unsigned int u = __builtin_bit_cast(unsigned int, f);
  u = (u + 0x7fffu + ((u >> 16) & 1u)) >> 16;
  return (unsigned short)u;
}

__device__ __forceinline__ void lds_load16(const unsigned short* g, unsigned short* l) {
  __builtin_amdgcn_global_load_lds(
      (const __attribute__((address_space(1))) void*)g,
      (__attribute__((address_space(3))) void*)l, 16, 0, 0);
}

template<int N> __device__ __forceinline__ void vmcnt_wait() {
  if constexpr (N == 0)      asm volatile("s_waitcnt vmcnt(0)" ::: "memory");
  else if constexpr (N == 3) asm volatile("s_waitcnt vmcnt(3)" ::: "memory");
  else if constexpr (N == 4) asm volatile("s_waitcnt vmcnt(4)" ::: "memory");
  else if constexpr (N == 6) asm volatile("s_waitcnt vmcnt(6)" ::: "memory");
  else                       asm volatile("s_waitcnt vmcnt(8)" ::: "memory");
}

// ---------------- prep kernels (2 launches total) ----------------

// f32->bf16 conversion of x (all 8192 blocks) + gate softmax & tg aug columns
// (first 64 blocks only; independent memory streams, same stream ordering).
__global__ void conv_gate_kernel(const float* __restrict__ in, unsigned int* __restrict__ out,
                                 long n8,
                                 const int* __restrict__ dom, const float* __restrict__ emb,
                                 const float* __restrict__ gW, const float* __restrict__ gb,
                                 float* __restrict__ gate, unsigned short* __restrict__ tg) {
  long i = (long)blockIdx.x * blockDim.x + threadIdx.x;
  if (i < n8) {
    float4 a = ((const float4*)in)[i * 2];
    float4 b = ((const float4*)in)[i * 2 + 1];
    uint4 o;
    o.x = f2b(a.x) | ((unsigned)f2b(a.y) << 16);
    o.y = f2b(a.z) | ((unsigned)f2b(a.w) << 16);
    o.z = f2b(b.x) | ((unsigned)f2b(b.y) << 16);
    o.w = f2b(b.z) | ((unsigned)f2b(b.w) << 16);
    ((uint4*)out)[i] = o;
  }
  if (blockIdx.x < M_ROWS / 256) {
    int r = blockIdx.x * 256 + threadIdx.x;     // one row per thread
    int d = dom[r];
    float e0 = emb[d*4+0], e1 = emb[d*4+1], e2 = emb[d*4+2], e3 = emb[d*4+3];
    float l[8]; float mx = -1e30f;
#pragma unroll
    for (int j = 0; j < 8; j++) {
      l[j] = e0*gW[j] + e1*gW[8+j] + e2*gW[16+j] + e3*gW[24+j] + gb[j];
      mx = fmaxf(mx, l[j]);
    }
    float s = 0.f;
#pragma unroll
    for (int j = 0; j < 8; j++) { l[j] = __expf(l[j] - mx); s += l[j]; }
    float inv = 1.0f / s;
    unsigned int g[4];
#pragma unroll
    for (int j = 0; j < 8; j++) {
      float v = l[j] * inv;
      gate[r*8+j] = v;
      unsigned int b = f2b(v);
      if (j & 1) g[j >> 1] |= b << 16; else g[j >> 1] = b;
    }
    uint4* dst = (uint4*)&tg[(long)r * KAUG + 128];
    dst[0] = make_uint4(g[0], g[1], g[2], g[3]);
    uint4 z4 = make_uint4(0, 0, 0, 0);
#pragma unroll
    for (int q = 1; q < 8; q++) dst[q] = z4;
  }
}

// Unified weight prep. blockIdx.z: 0-2 -> Wt[layer z]; 3-5 -> Aft[z-3]; 6-8 -> Bft[z-6].
// Grid (32, 32, 9); out-of-range blocks return immediately.
// Wt[n*K+k]=bf16(W[k*N+n]);  Aft[(e*16+r)*P+p]=bf16(A[e][p][r]);
// Bft[n*KAUG+kk]: kk<128 -> B[kk*H+n]; kk in [128,136) -> lb[kk-128][n]; else 0.
__global__ void build_all(const float* __restrict__ w0, const float* __restrict__ w1,
                          const float* __restrict__ w2,
                          const float* __restrict__ a0, const float* __restrict__ a1,
                          const float* __restrict__ a2,
                          const float* __restrict__ b0, const float* __restrict__ b1,
                          const float* __restrict__ b2,
                          const float* __restrict__ l0, const float* __restrict__ l1,
                          const float* __restrict__ l2,
                          unsigned short* __restrict__ wt0, unsigned short* __restrict__ wt1,
                          unsigned short* __restrict__ wt2,
                          unsigned short* __restrict__ at0, unsigned short* __restrict__ at1,
                          unsigned short* __restrict__ at2,
                          unsigned short* __restrict__ bt0, unsigned short* __restrict__ bt1,
                          unsigned short* __restrict__ bt2) {
  __shared__ float tl[1088];                 // max(32*33, 64*17)
  const int zz = blockIdx.z;
  const int tx = threadIdx.x & 31, ty = threadIdx.x >> 5;
  if (zz < 3) {                              // ---- Wt ----
    const int z = zz;
    const float* W = z == 0 ? w0 : (z == 1 ? w1 : w2);
    unsigned short* Wt = z == 0 ? wt0 : (z == 1 ? wt1 : wt2);
    int K = (z == 2) ? 512 : 1024;
    int N = (z == 0) ? 1024 : (z == 1 ? 512 : 256);
    int n0 = blockIdx.x * 32, k0 = blockIdx.y * 32;
    if (n0 >= N || k0 >= K) return;
#pragma unroll
    for (int i = 0; i < 32; i += 8)
      tl[(ty + i) * 33 + tx] = W[(long)(k0 + ty + i) * N + n0 + tx];
    __syncthreads();
#pragma unroll
    for (int i = 0; i < 32; i += 8)
      Wt[(long)(n0 + ty + i) * K + k0 + tx] = f2b(tl[tx * 33 + ty + i]);
  } else if (zz < 6) {                       // ---- Aft ----
    const int z = zz - 3;
    const float* A = z == 0 ? a0 : (z == 1 ? a1 : a2);
    unsigned short* Aft = z == 0 ? at0 : (z == 1 ? at1 : at2);
    int P = (z == 2) ? 512 : 1024;
    long p0 = (long)blockIdx.x * 64;
    if (p0 >= P || blockIdx.y >= 8) return;
    int e = blockIdx.y;
    int t = threadIdx.x;
#pragma unroll
    for (int pass = 0; pass < 4; pass++) {
      int idx = t + pass * 256;
      int pl = idx >> 4, r = idx & 15;
      tl[pl * 17 + r] = A[((long)e * P + p0 + pl) * 16 + r];
    }
    __syncthreads();
#pragma unroll
    for (int pass = 0; pass < 4; pass++) {
      int idx = t + pass * 256;
      int r = idx >> 6, pl = idx & 63;
      Aft[(long)(e * 16 + r) * P + p0 + pl] = f2b(tl[pl * 17 + r]);
    }
  } else {                                   // ---- Bft ----
    const int z = zz - 6;
    const float* Bm = z == 0 ? b0 : (z == 1 ? b1 : b2);
    const float* lb = z == 0 ? l0 : (z == 1 ? l1 : l2);
    unsigned short* Bft = z == 0 ? bt0 : (z == 1 ? bt1 : bt2);
    int H = (z == 0) ? 1024 : (z == 1 ? 512 : 256);
    int n0 = blockIdx.x * 32, kk0 = blockIdx.y * 32;
    if (n0 >= H || kk0 >= KAUG) return;
#pragma unroll
    for (int i = 0; i < 32; i += 8) {
      int kk = kk0 + ty + i;
      float v;
      if (kk < 128)       v = Bm[(long)kk * H + n0 + tx];
      else if (kk < 136)  v = lb[(long)(kk - 128) * H + n0 + tx];
      else                v = 0.f;
      tl[(ty + i) * 33 + tx] = v;
    }
    __syncthreads();
#pragma unroll
    for (int i = 0; i < 32; i += 8)
      Bft[(long)(n0 + ty + i) * KAUG + kk0 + tx] = f2b(tl[tx * 33 + ty + i]);
  }
}

// ---------------- fine-phase 128-wide GEMM (x@A) ----------------
// BM x 128 tile, BK=64, 512 threads = 8 waves (2M x 4N), 3 LDS buffers,
// tile t+2 staged during tile t; counted vmcnt, never 0 in-loop.
template<int MODE, int BM>
__global__ __launch_bounds__(512)
void gemm_mn(const unsigned short* __restrict__ A1, int lda1, int K1,
             const unsigned short* __restrict__ A2, int lda2, int K2,
             const unsigned short* __restrict__ Bt1, int ldb1,
             const unsigned short* __restrict__ Bt2, int ldb2,
             const float* __restrict__ bias,
             const float* __restrict__ gate,
             void* __restrict__ outp, int ldout) {
  constexpr int MFRAG = BM / 32;
  constexpr int ATOT = BM * 64;
  constexpr int BTOT = 128 * 64;
  constexpr int LA = BM / 64;
  constexpr int L = LA + 2;
  __shared__ __attribute__((aligned(16))) unsigned short lds[3 * ATOT + 3 * BTOT];

  const int t = threadIdx.x;
  const int lane = t & 63, wave = t >> 6;
  const int wr = wave >> 2, wc = wave & 3;
  const int rl = lane & 15, kg = lane >> 4;
  const int row0 = blockIdx.x * BM, col0 = blockIdx.y * 128;

  const int sr = t >> 3;
  const int sk = ((t & 7) ^ (sr & 7)) * 8;

  f32x4 acc[MFRAG][2];
#pragma unroll
  for (int m = 0; m < MFRAG; m++)
#pragma unroll
    for (int n = 0; n < 2; n++) acc[m][n] = (f32x4){0.f, 0.f, 0.f, 0.f};

  auto stageA = [&](int buf, int kt) {
    const unsigned short* src; long ld; int kl;
    if (kt < K1) { src = A1; ld = lda1; kl = kt; }
    else         { src = A2; ld = lda2; kl = kt - K1; }
    unsigned short* d = &lds[buf * ATOT + t * 8];
    const unsigned short* s = src + (long)(row0 + sr) * ld + kl + sk;
#pragma unroll
    for (int i = 0; i < LA; i++)
      lds_load16(s + (long)(i * 64) * ld, d + i * 4096);
  };
  auto stageB = [&](int buf, int kt) {
    const unsigned short* src; long ld; int kl;
    if (kt < K1) { src = Bt1; ld = ldb1; kl = kt; }
    else         { src = Bt2; ld = ldb2; kl = kt - K1; }
    unsigned short* d = &lds[3 * ATOT + buf * BTOT + t * 8];
    const unsigned short* s = src + (long)(col0 + sr) * ld + kl + sk;
    lds_load16(s, d);
    lds_load16(s + 64 * ld, d + 4096);
  };
  auto ldA = [&](int buf, int mg, int ks) {
    int lr = wr * (BM / 2) + mg * 16 + rl;
    int sc = (ks * 4 + kg) ^ (lr & 7);
    return *(const bf16x8*)&lds[buf * ATOT + lr * 64 + sc * 8];
  };
  auto ldB = [&](int buf, int n, int ks) {
    int cr = wc * 32 + n * 16 + rl;
    int sc = (ks * 4 + kg) ^ (cr & 7);
    return *(const bf16x8*)&lds[3 * ATOT + buf * BTOT + cr * 64 + sc * 8];
  };

  const int Ktot = K1 + K2;
  const int NT = Ktot / 64;

  stageA(0, 0); stageB(0, 0);
  stageA(1, 64); stageB(1, 64);
  vmcnt_wait<L>();
  __builtin_amdgcn_s_barrier();

  int bcur = 0;
  bf16x8 Bfv[2][2];
  for (int tt = 0; tt < NT; ++tt) {
    int bpf = bcur + 2; if (bpf > 2) bpf -= 3;
    const bool pf = (tt + 2 < NT);
    bf16x8 Af[(MFRAG + 1) / 2][2];
#pragma unroll
    for (int m = 0; m < MFRAG / 2; m++) { Af[m][0] = ldA(bcur, m, 0); Af[m][1] = ldA(bcur, m, 1); }
#pragma unroll
    for (int n = 0; n < 2; n++) { Bfv[n][0] = ldB(bcur, n, 0); Bfv[n][1] = ldB(bcur, n, 1); }
    if (pf) stageA(bpf, (tt + 2) * 64);
    __builtin_amdgcn_s_barrier();
    asm volatile("s_waitcnt lgkmcnt(0)" ::: "memory");
    __builtin_amdgcn_sched_barrier(0);
    __builtin_amdgcn_s_setprio(1);
#pragma unroll
    for (int m = 0; m < MFRAG / 2; m++)
#pragma unroll
      for (int n = 0; n < 2; n++) {
        acc[m][n] = __builtin_amdgcn_mfma_f32_16x16x32_bf16(Af[m][0], Bfv[n][0], acc[m][n], 0, 0, 0);
        acc[m][n] = __builtin_amdgcn_mfma_f32_16x16x32_bf16(Af[m][1], Bfv[n][1], acc[m][n], 0, 0, 0);
      }
    __builtin_amdgcn_s_setprio(0);
    __builtin_amdgcn_s_barrier();
#pragma unroll
    for (int m = 0; m < MFRAG / 2; m++) { Af[m][0] = ldA(bcur, MFRAG / 2 + m, 0); Af[m][1] = ldA(bcur, MFRAG / 2 + m, 1); }
    if (pf) stageB(bpf, (tt + 2) * 64);
    if (tt + 1 < NT) vmcnt_wait<L>();
    else             vmcnt_wait<0>();
    __builtin_amdgcn_s_barrier();
    asm volatile("s_waitcnt lgkmcnt(0)" ::: "memory");
    __builtin_amdgcn_sched_barrier(0);
    __builtin_amdgcn_s_setprio(1);
#pragma unroll
    for (int m = 0; m < MFRAG / 2; m++)
#pragma unroll
      for (int n = 0; n < 2; n++) {
        acc[MFRAG / 2 + m][n] = __builtin_amdgcn_mfma_f32_16x16x32_bf16(Af[m][0], Bfv[n][0], acc[MFRAG / 2 + m][n], 0, 0, 0);
        acc[MFRAG / 2 + m][n] = __builtin_amdgcn_mfma_f32_16x16x32_bf16(Af[m][1], Bfv[n][1], acc[MFRAG / 2 + m][n], 0, 0, 0);
      }
    __builtin_amdgcn_s_setprio(0);
    __builtin_amdgcn_s_barrier();
    bcur = bcur == 2 ? 0 : bcur + 1;
  }

#pragma unroll
  for (int m = 0; m < MFRAG; m++)
#pragma unroll
    for (int n = 0; n < 2; n++)
#pragma unroll
      for (int j = 0; j < 4; j++) {
        int row = row0 + wr * (BM / 2) + m * 16 + kg * 4 + j;
        int col = col0 + wc * 32 + n * 16 + rl;
        float v = acc[m][n][j];
        if (MODE == 0) {
          v *= gate[row * 8 + (col >> 4)];
          ((unsigned short*)outp)[(long)row * ldout + col] = f2b(v);
        } else {
          v += bias[col];
          v = fmaxf(v, 0.f);
          if (MODE == 1) ((unsigned short*)outp)[(long)row * ldout + col] = f2b(v);
          else           ((float*)outp)[(long)row * ldout + col] = v;
        }
      }
}

// ---------------- gemm2b (main GEMMs): BK=64, 2 buffers, 2 blocks/CU ----------------
// BM x 128 tile, 256 threads = 4 waves (2M x 2N), per-wave BM/2 x 64.
// Per K-tile: issue all prefetch gload_lds FIRST, then 2 {ds_read, lgkm0, MFMA}
// phases, then vmcnt(0) + ONE barrier per tile. Swizzle: chunk c of row r at c^(r&7).
template<int MODE, int BM>
__global__ __launch_bounds__(256, 4)
void gemm2b(const unsigned short* __restrict__ A1, int lda1, int K1,
            const unsigned short* __restrict__ A2, int lda2, int K2,
            const unsigned short* __restrict__ Bt1, int ldb1,
            const unsigned short* __restrict__ Bt2, int ldb2,
            const float* __restrict__ bias,
            const float* __restrict__ gate,
            void* __restrict__ outp, int ldout) {
  constexpr int ATOT = BM * 64;
  constexpr int BTOT = 128 * 64;
  constexpr int MF = BM / 64;
  constexpr int LA = BM / 32;
  __shared__ __attribute__((aligned(16))) unsigned short lds[2 * ATOT + 2 * BTOT];

  const int t = threadIdx.x;
  const int lane = t & 63, wave = t >> 6;
  const int wr = wave >> 1, wc = wave & 1;
  const int rl = lane & 15, kg = lane >> 4;
  const int row0 = blockIdx.x * BM, col0 = blockIdx.y * 128;

  const int sr = t >> 3;
  const int sk = ((t & 7) ^ (sr & 7)) * 8;

  f32x4 acc[2 * MF][4];
#pragma unroll
  for (int m = 0; m < 2 * MF; m++)
#pragma unroll
    for (int n = 0; n < 4; n++) acc[m][n] = (f32x4){0.f, 0.f, 0.f, 0.f};

  auto stageA = [&](int buf, int kt) {
    const unsigned short* src; long ld; int kl;
    if (kt < K1) { src = A1; ld = lda1; kl = kt; }
    else         { src = A2; ld = lda2; kl = kt - K1; }
    unsigned short* d = &lds[buf * ATOT + t * 8];
    const unsigned short* s = src + (long)(row0 + sr) * ld + kl + sk;
#pragma unroll
    for (int i = 0; i < LA; i++)
      lds_load16(s + (long)(i * 32) * ld, d + i * 2048);
  };
  auto stageB = [&](int buf, int kt) {
    const unsigned short* src; long ld; int kl;
    if (kt < K1) { src = Bt1; ld = ldb1; kl = kt; }
    else         { src = Bt2; ld = ldb2; kl = kt - K1; }
    unsigned short* d = &lds[2 * ATOT + buf * BTOT + t * 8];
    const unsigned short* s = src + (long)(col0 + sr) * ld + kl + sk;
#pragma unroll
    for (int i = 0; i < 4; i++)
      lds_load16(s + (long)(i * 32) * ld, d + i * 2048);
  };
  auto ldA = [&](int buf, int mf, int ks) {
    int lr = wr * (BM / 2) + mf * 16 + rl;
    int sc = (ks * 4 + kg) ^ (lr & 7);
    return *(const bf16x8*)&lds[buf * ATOT + lr * 64 + sc * 8];
  };
  auto ldB = [&](int buf, int nf, int ks) {
    int cr = wc * 64 + nf * 16 + rl;
    int sc = (ks * 4 + kg) ^ (cr & 7);
    return *(const bf16x8*)&lds[2 * ATOT + buf * BTOT + cr * 64 + sc * 8];
  };

  const int NT = (K1 + K2) / 64;

  stageA(0, 0); stageB(0, 0);
  asm volatile("s_waitcnt vmcnt(0)" ::: "memory");
  __builtin_amdgcn_s_barrier();

  int cur = 0;
  for (int tt = 0; tt < NT; ++tt) {
    const bool pf = (tt + 1 < NT);
    const int kt1 = (tt + 1) * 64;
    if (pf) { stageA(cur ^ 1, kt1); stageB(cur ^ 1, kt1); }
    bf16x8 Am_[MF][2], Bf[4][2];
#pragma unroll
    for (int mf = 0; mf < MF; mf++) { Am_[mf][0] = ldA(cur, mf, 0); Am_[mf][1] = ldA(cur, mf, 1); }
#pragma unroll
    for (int nf = 0; nf < 4; nf++) { Bf[nf][0] = ldB(cur, nf, 0); Bf[nf][1] = ldB(cur, nf, 1); }
    asm volatile("s_waitcnt lgkmcnt(0)" ::: "memory");
    __builtin_amdgcn_sched_barrier(0);
    __builtin_amdgcn_s_setprio(1);
#pragma unroll
    for (int mf = 0; mf < MF; mf++)
#pragma unroll
      for (int nf = 0; nf < 4; nf++) {
        acc[mf][nf] = __builtin_amdgcn_mfma_f32_16x16x32_bf16(Am_[mf][0], Bf[nf][0], acc[mf][nf], 0, 0, 0);
        acc[mf][nf] = __builtin_amdgcn_mfma_f32_16x16x32_bf16(Am_[mf][1], Bf[nf][1], acc[mf][nf], 0, 0, 0);
      }
    __builtin_amdgcn_s_setprio(0);
#pragma unroll
    for (int mf = 0; mf < MF; mf++) { Am_[mf][0] = ldA(cur, MF + mf, 0); Am_[mf][1] = ldA(cur, MF + mf, 1); }
    asm volatile("s_waitcnt lgkmcnt(0)" ::: "memory");
    __builtin_amdgcn_sched_barrier(0);
    __builtin_amdgcn_s_setprio(1);
#pragma unroll
    for (int mf = 0; mf < MF; mf++)
#pragma unroll
      for (int nf = 0; nf < 4; nf++) {
        acc[MF + mf][nf] = __builtin_amdgcn_mfma_f32_16x16x32_bf16(Am_[mf][0], Bf[nf][0], acc[MF + mf][nf], 0, 0, 0);
        acc[MF + mf][nf] = __builtin_amdgcn_mfma_f32_16x16x32_bf16(Am_[mf][1], Bf[nf][1], acc[MF + mf][nf], 0, 0, 0);
      }
    __builtin_amdgcn_s_setprio(0);
    if (pf) asm volatile("s_waitcnt vmcnt(0)" ::: "memory");
    __builtin_amdgcn_s_barrier();
    cur ^= 1;
  }

#pragma unroll
  for (int m = 0; m < 2 * MF; m++)
#pragma unroll
    for (int n = 0; n < 4; n++)
#pragma unroll
      for (int j = 0; j < 4; j++) {
        int row = row0 + wr * (BM / 2) + m * 16 + kg * 4 + j;
        int col = col0 + wc * 64 + n * 16 + rl;
        float v = acc[m][n][j];
        if (MODE == 0) {
          v *= gate[row * 8 + (col >> 4)];
          ((unsigned short*)outp)[(long)row * ldout + col] = f2b(v);
        } else {
          v += bias[col];
          v = fmaxf(v, 0.f);
          if (MODE == 1) ((unsigned short*)outp)[(long)row * ldout + col] = f2b(v);
          else           ((float*)outp)[(long)row * ldout + col] = v;
        }
      }
}

// ---------------- launch ----------------

extern "C" void kernel_launch(void* const* d_in, const int* in_sizes, int n_in,
                              void* d_out, int out_size, void* d_ws, size_t ws_size,
                              hipStream_t stream) {
  (void)in_sizes; (void)n_in; (void)out_size; (void)ws_size;
  const float* dnn = (const float*)d_in[0];
  const int*   dom = (const int*)d_in[1];
  const float* emb = (const float*)d_in[2];
  const float* gW  = (const float*)d_in[3];
  const float* gb  = (const float*)d_in[4];
  const float* Wm[3]  = {(const float*)d_in[5],  (const float*)d_in[10], (const float*)d_in[15]};
  const float* bm[3]  = {(const float*)d_in[6],  (const float*)d_in[11], (const float*)d_in[16]};
  const float* Am[3]  = {(const float*)d_in[7],  (const float*)d_in[12], (const float*)d_in[17]};
  const float* Bm[3]  = {(const float*)d_in[8],  (const float*)d_in[13], (const float*)d_in[18]};
  const float* lbm[3] = {(const float*)d_in[9],  (const float*)d_in[14], (const float*)d_in[19]};

  const int M = M_ROWS;
  const int dIn[3]  = {1024, 1024, 512};
  const int dOutN[3] = {1024, 512, 256};

  char* p = (char*)d_ws;
  auto carve = [&](size_t bytes) { char* r = p; p += (bytes + 255) & ~(size_t)255; return r; };
  float* gate = (float*)carve((size_t)M * 8 * sizeof(float));
  unsigned short* xb0 = (unsigned short*)carve((size_t)M * 1024 * 2);
  unsigned short* xb1 = (unsigned short*)carve((size_t)M * 1024 * 2);
  unsigned short* tg  = (unsigned short*)carve((size_t)M * KAUG * 2);
  unsigned short *Wt[3], *Aft[3], *Bft[3];
  for (int l = 0; l < 3; l++) {
    Wt[l]  = (unsigned short*)carve((size_t)dOutN[l] * dIn[l] * 2);
    Aft[l] = (unsigned short*)carve((size_t)128 * dIn[l] * 2);
    Bft[l] = (unsigned short*)carve((size_t)dOutN[l] * KAUG * 2);
  }

  {
    long n8 = (long)M * 1024 / 8;
    conv_gate_kernel<<<(int)((n8 + 255) / 256), 256, 0, stream>>>(
        dnn, (unsigned int*)xb0, n8, dom, emb, gW, gb, gate, tg);
  }
  build_all<<<dim3(32, 32, 9), 256, 0, stream>>>(
      Wm[0], Wm[1], Wm[2], Am[0], Am[1], Am[2], Bm[0], Bm[1], Bm[2],
      lbm[0], lbm[1], lbm[2],
      Wt[0], Wt[1], Wt[2], Aft[0], Aft[1], Aft[2], Bft[0], Bft[1], Bft[2]);

  const unsigned short* xin = xb0;
  for (int l = 0; l < 3; l++) {
    int K1 = dIn[l], N = dOutN[l];
    // tg[:, :128] = gate-scaled x @ A_flat  (deep-pipelined, 256 blocks)
    gemm_mn<0, 64><<<dim3(M / 64, 1), 512, 0, stream>>>(
        xin, K1, K1, nullptr, 0, 0, Aft[l], K1, nullptr, 0, nullptr, gate, (void*)tg, KAUG);
    // out = relu(x @ W + tg_aug @ B_aug + bias)
    if (l == 0)
      gemm2b<1, 128><<<dim3(M / 128, N / 128), 256, 0, stream>>>(
          xin, K1, K1, tg, KAUG, KAUG, Wt[l], K1, Bft[l], KAUG, bm[l], nullptr, (void*)xb1, N);
    else if (l == 1)
      gemm2b<1, 128><<<dim3(M / 128, N / 128), 256, 0, stream>>>(
          xin, K1, K1, tg, KAUG, KAUG, Wt[l], K1, Bft[l], KAUG, bm[l], nullptr, (void*)xb0, N);
    else
      gemm2b<2, 64><<<dim3(M / 64, N / 128), 256, 0, stream>>>(
          xin, K1, K1, tg, KAUG, KAUG, Wt[l], K1, Bft[l], KAUG, bm[l], nullptr, d_out, N);
    xin = (l == 0) ? xb1 : xb0;
  }
}